// Round 1
// baseline (1297.409 us; speedup 1.0000x reference)
//
#include <hip/hip_runtime.h>
#include <math.h>

// LocalizationLoss: B rows of [4 box preds | 1000 logits] (fp32).
// loss = mean_rows( 0.25*sum((box_pred - box_true)^2) + (logsumexp(logits) - logits[cls]) )
// One wave per row, 2 rows in flight per wave (MLP/ILP).
// Two-phase logsumexp: butterfly max -> exp vs final max -> butterfly sum
// (16 exps/row, no dependent-exp merge chain).
// Class logit extracted from registers (cls is wave-uniform) -- no dependent gather load.

#define ROWLEN 1004
#define NVEC   250   // 1000 logits / 4
#define TAIL   58    // NVEC - 192

#define ESUM4(v, m) (__expf((v).x - (m)) + __expf((v).y - (m)) + \
                     __expf((v).z - (m)) + __expf((v).w - (m)))

__global__ __launch_bounds__(256) void loc_loss_kernel(
    const float* __restrict__ output,
    const float* __restrict__ target,
    float* __restrict__ out,
    int n_rows, float inv_n)
{
    const int lane          = threadIdx.x & 63;
    const int wave_in_block = threadIdx.x >> 6;
    const int wave_id       = blockIdx.x * 4 + wave_in_block;
    const int num_waves     = gridDim.x * 4;

    float acc = 0.0f;

    for (int rowA = wave_id; rowA < n_rows; rowA += 2 * num_waves) {
        const int  rowB  = rowA + num_waves;
        const bool hasB  = rowB < n_rows;
        const int  rowB_ = hasB ? rowB : rowA;

        const float* rbA = output + (size_t)rowA  * ROWLEN;
        const float* rbB = output + (size_t)rowB_ * ROWLEN;
        const float* trA = target + (size_t)rowA  * 5;
        const float* trB = target + (size_t)rowB_ * 5;

        // ---- issue all global loads up front: 8 coalesced 1KB vector loads ----
        const float4* lbA = (const float4*)(rbA + 4);
        const float4* lbB = (const float4*)(rbB + 4);

        float4 a0 = lbA[lane];
        float4 b0 = lbB[lane];
        float4 a1 = lbA[lane + 64];
        float4 b1 = lbB[lane + 64];
        float4 a2 = lbA[lane + 128];
        float4 b2 = lbB[lane + 128];
        float4 a3, b3;
        if (lane < TAIL) {
            a3 = lbA[lane + 192];
            b3 = lbB[lane + 192];
        } else {
            a3.x = a3.y = a3.z = a3.w = -INFINITY;
            b3.x = b3.y = b3.z = b3.w = -INFINITY;
        }

        // uniform same-address loads (hardware-coalesced to one transaction, broadcast)
        float4 bpA = *(const float4*)rbA;   // row stride 4016 B -> 16B aligned
        float4 bpB = *(const float4*)rbB;
        float a_t0 = trA[0], a_t1 = trA[1], a_t2 = trA[2], a_t3 = trA[3];
        int   a_cls = (int)trA[4];
        float b_t0 = trB[0], b_t1 = trB[1], b_t2 = trB[2], b_t3 = trB[3];
        int   b_cls = (int)trB[4];

        // ---- lane-local max (A/B chains interleaved for ILP) ----
        float mA = fmaxf(fmaxf(fmaxf(a0.x, a0.y), fmaxf(a0.z, a0.w)),
                         fmaxf(fmaxf(a1.x, a1.y), fmaxf(a1.z, a1.w)));
        float mB = fmaxf(fmaxf(fmaxf(b0.x, b0.y), fmaxf(b0.z, b0.w)),
                         fmaxf(fmaxf(b1.x, b1.y), fmaxf(b1.z, b1.w)));
        mA = fmaxf(mA, fmaxf(fmaxf(a2.x, a2.y), fmaxf(a2.z, a2.w)));
        mB = fmaxf(mB, fmaxf(fmaxf(b2.x, b2.y), fmaxf(b2.z, b2.w)));
        mA = fmaxf(mA, fmaxf(fmaxf(a3.x, a3.y), fmaxf(a3.z, a3.w)));
        mB = fmaxf(mB, fmaxf(fmaxf(b3.x, b3.y), fmaxf(b3.z, b3.w)));

        // ---- wave max butterfly (shfl+max only, no exps) ----
        #pragma unroll
        for (int off = 1; off < 64; off <<= 1) {
            mA = fmaxf(mA, __shfl_xor(mA, off, 64));
            mB = fmaxf(mB, __shfl_xor(mB, off, 64));
        }

        // ---- class logit straight out of registers (cls is wave-uniform) ----
        int avi = a_cls >> 2, ac = a_cls & 3, asrc = avi & 63, aj = avi >> 6;
        int bvi = b_cls >> 2, bc = b_cls & 3, bsrc = bvi & 63, bj = bvi >> 6;
        float4 avj = (aj == 0) ? a0 : (aj == 1) ? a1 : (aj == 2) ? a2 : a3;
        float4 bvj = (bj == 0) ? b0 : (bj == 1) ? b1 : (bj == 2) ? b2 : b3;
        float acand = (ac == 0) ? avj.x : (ac == 1) ? avj.y : (ac == 2) ? avj.z : avj.w;
        float bcand = (bc == 0) ? bvj.x : (bc == 1) ? bvj.y : (bc == 2) ? bvj.z : bvj.w;
        float a_logit = __shfl(acand, asrc, 64);
        float b_logit = __shfl(bcand, bsrc, 64);

        // ---- exp vs the final max: single pass, exp(-inf - m) == 0 handles the tail ----
        float sA = ESUM4(a0, mA) + ESUM4(a1, mA) + ESUM4(a2, mA) + ESUM4(a3, mA);
        float sB = ESUM4(b0, mB) + ESUM4(b1, mB) + ESUM4(b2, mB) + ESUM4(b3, mB);

        // ---- wave sum butterfly ----
        #pragma unroll
        for (int off = 1; off < 64; off <<= 1) {
            sA += __shfl_xor(sA, off, 64);
            sB += __shfl_xor(sB, off, 64);
        }

        if (lane == 0) {
            {
                float lse = mA + __logf(sA);
                float cx = (a_t0 + a_t2) * 0.5f;
                float cy = (a_t1 + a_t3) * 0.5f;
                float w  = a_t2 - a_t0;
                float h  = a_t3 - a_t1;
                float dx = bpA.x - cx, dy = bpA.y - cy, dw = bpA.z - w, dh = bpA.w - h;
                acc += (dx * dx + dy * dy + dw * dw + dh * dh) * 0.25f + (lse - a_logit);
            }
            if (hasB) {
                float lse = mB + __logf(sB);
                float cx = (b_t0 + b_t2) * 0.5f;
                float cy = (b_t1 + b_t3) * 0.5f;
                float w  = b_t2 - b_t0;
                float h  = b_t3 - b_t1;
                float dx = bpB.x - cx, dy = bpB.y - cy, dw = bpB.z - w, dh = bpB.w - h;
                acc += (dx * dx + dy * dy + dw * dw + dh * dh) * 0.25f + (lse - b_logit);
            }
        }
    }

    __shared__ float part[4];
    if (lane == 0) part[wave_in_block] = acc;
    __syncthreads();
    if (threadIdx.x == 0) {
        float tot = (part[0] + part[1] + part[2] + part[3]) * inv_n;
        atomicAdd(out, tot);
    }
}

extern "C" void kernel_launch(void* const* d_in, const int* in_sizes, int n_in,
                              void* d_out, int out_size, void* d_ws, size_t ws_size,
                              hipStream_t stream) {
    const float* output = (const float*)d_in[0];
    const float* target = (const float*)d_in[1];
    float* out = (float*)d_out;

    int n_rows = in_sizes[0] / ROWLEN;
    float inv_n = 1.0f / (float)n_rows;

    // d_out is poisoned to 0xAA before every launch — zero it for the atomics
    hipMemsetAsync(out, 0, out_size * sizeof(float), stream);

    loc_loss_kernel<<<4096, 256, 0, stream>>>(output, target, out, n_rows, inv_n);
}